// Round 13
// baseline (883.170 us; speedup 1.0000x reference)
//
#include <hip/hip_runtime.h>
#include <hip/hip_bf16.h>
#include <cstdint>

typedef unsigned short u16;
typedef unsigned int   u32;
typedef _Float16 f16;
typedef __bf16    bf16x8 __attribute__((ext_vector_type(8)));
typedef _Float16  f16x8  __attribute__((ext_vector_type(8)));
typedef float     f32x4  __attribute__((ext_vector_type(4)));

#define MFMAB(a,b,c) __builtin_amdgcn_mfma_f32_16x16x32_bf16((a),(b),(c),0,0,0)
#define MFMAH(a,b,c) __builtin_amdgcn_mfma_f32_16x16x32_f16((a),(b),(c),0,0,0)

#define LO_SCALE 4096.0f
#define INV_LO   (1.0f/4096.0f)
#define YSTR (4352ull * 1024ull)

__device__ __forceinline__ float bf2f(u16 u) {
    union { unsigned int i; float f; } c; c.i = ((unsigned int)u) << 16; return c.f;
}
__device__ __forceinline__ u16 f2bf(float f) {
    __bf16 b = (__bf16)f;
    return __builtin_bit_cast(unsigned short, b);
}
__device__ __forceinline__ void fsplit(float v, f16& h, f16& l) {
    f16 hh = (f16)v;
    h = hh;
    l = (f16)((v - (float)hh) * LO_SCALE);
}
__device__ __forceinline__ u32 packh2(f16 a, f16 b) {
    u32 x = (u32)__builtin_bit_cast(u16, a);
    u32 y = (u32)__builtin_bit_cast(u16, b);
    return x | (y << 16);
}
__device__ __forceinline__ void gload_lds16(const void* g, void* l) {
    __builtin_amdgcn_global_load_lds(
        (const __attribute__((address_space(1))) void*)g,
        (__attribute__((address_space(3))) void*)l, 16, 0, 0);
}

// ---------------- weight transpose f32[R][C] -> bf16 [C][R], batched over z -----
__global__ void transpose_wb(const float* __restrict__ in, u16* __restrict__ out,
                             int R, int C) {
    __shared__ float tile[32][33];
    const size_t zb = (size_t)blockIdx.z * (size_t)R * (size_t)C;
    in  += zb; out += zb;
    int c0 = blockIdx.x * 32, r0 = blockIdx.y * 32;
    int tx = threadIdx.x & 31, ty = threadIdx.x >> 5;  // 256 threads: 32x8
#pragma unroll
    for (int i = 0; i < 4; ++i)
        tile[ty + 8*i][tx] = in[(size_t)(r0 + ty + 8*i) * C + c0 + tx];
    __syncthreads();
#pragma unroll
    for (int i = 0; i < 4; ++i)
        out[(size_t)(c0 + ty + 8*i) * R + r0 + tx] = f2bf(tile[tx][ty + 8*i]);
}

// ---------------- weight transpose f32[R][C] -> f16 split [C][R] x2 -------------
__global__ void transpose_wsplit(const float* __restrict__ in, f16* __restrict__ oh,
                                 f16* __restrict__ ol, int R, int C) {
    __shared__ float tile[32][33];
    int c0 = blockIdx.x * 32, r0 = blockIdx.y * 32;
    int tx = threadIdx.x & 31, ty = threadIdx.x >> 5;
#pragma unroll
    for (int i = 0; i < 4; ++i)
        tile[ty + 8*i][tx] = in[(size_t)(r0 + ty + 8*i) * C + c0 + tx];
    __syncthreads();
#pragma unroll
    for (int i = 0; i < 4; ++i) {
        float v = tile[tx][ty + 8*i];
        f16 h, l; fsplit(v, h, l);
        size_t o = (size_t)(c0 + ty + 8*i) * R + r0 + tx;
        oh[o] = h; ol[o] = l;
    }
}

// ---------------- w1/w3 interleaved transpose: f32[1024][2816] -> bf16 W13T -----
// out row for col j: (j>>6)*128 + (j&63) + gofs  (gofs=0 for w1, 64 for w3)
__global__ void transpose_w13(const float* __restrict__ in, u16* __restrict__ out,
                              int gofs) {
    __shared__ float tile[32][33];
    in  += (size_t)blockIdx.z * 1024 * 2816;
    u16* oute = out + (size_t)blockIdx.z * 5632 * 1024;
    int c0 = blockIdx.x * 32, r0 = blockIdx.y * 32;
    int tx = threadIdx.x & 31, ty = threadIdx.x >> 5;
#pragma unroll
    for (int i = 0; i < 4; ++i)
        tile[ty + 8*i][tx] = in[(size_t)(r0 + ty + 8*i) * 2816 + c0 + tx];
    __syncthreads();
#pragma unroll
    for (int i = 0; i < 4; ++i) {
        int cc = c0 + ty + 8*i;
        int orow = ((cc >> 6) << 7) + (cc & 63) + gofs;
        oute[(size_t)orow * 1024 + r0 + tx] = f2bf(tile[tx][ty + 8*i]);
    }
}

// ---------------- RMSNorm f32 -> f16 split (d = 1024, 256 thr/row) --------------
__global__ void rmsnorm_split(const float* __restrict__ x, const float* __restrict__ wt,
                              f16* __restrict__ oh, f16* __restrict__ ol) {
    const int row = blockIdx.x, t = threadIdx.x;
    const float4 xv = reinterpret_cast<const float4*>(x + (size_t)row * 1024)[t];
    float ss = xv.x*xv.x + xv.y*xv.y + xv.z*xv.z + xv.w*xv.w;
#pragma unroll
    for (int o = 32; o >= 1; o >>= 1) ss += __shfl_xor(ss, o);
    __shared__ float red[4];
    if ((t & 63) == 0) red[t >> 6] = ss;
    __syncthreads();
    float tot = red[0] + red[1] + red[2] + red[3];
    float inv = rsqrtf(tot * (1.f/1024.f) + 1e-6f);
    const float4 wv = reinterpret_cast<const float4*>(wt)[t];
    float v[4] = { xv.x*inv*wv.x, xv.y*inv*wv.y, xv.z*inv*wv.z, xv.w*inv*wv.w };
    union { f16 f[4]; ushort4 u; } H, L;
#pragma unroll
    for (int j = 0; j < 4; ++j) fsplit(v[j], H.f[j], L.f[j]);
    reinterpret_cast<ushort4*>((u16*)oh + (size_t)row * 1024)[t] = H.u;
    reinterpret_cast<ushort4*>((u16*)ol + (size_t)row * 1024)[t] = L.u;
}

// ---------------- RMSNorm f32 -> bf16 (for MoE input) ---------------------------
__global__ void rmsnorm_bf16(const float* __restrict__ x, const float* __restrict__ wt,
                             u16* __restrict__ out) {
    const int row = blockIdx.x, t = threadIdx.x;
    const float4 xv = reinterpret_cast<const float4*>(x + (size_t)row * 1024)[t];
    float ss = xv.x*xv.x + xv.y*xv.y + xv.z*xv.z + xv.w*xv.w;
#pragma unroll
    for (int o = 32; o >= 1; o >>= 1) ss += __shfl_xor(ss, o);
    __shared__ float red[4];
    if ((t & 63) == 0) red[t >> 6] = ss;
    __syncthreads();
    float tot = red[0] + red[1] + red[2] + red[3];
    float inv = rsqrtf(tot * (1.f/1024.f) + 1e-6f);
    const float4 wv = reinterpret_cast<const float4*>(wt)[t];
    ushort4 r;
    r.x = f2bf(xv.x * inv * wv.x);
    r.y = f2bf(xv.y * inv * wv.y);
    r.z = f2bf(xv.z * inv * wv.z);
    r.w = f2bf(xv.w * inv * wv.w);
    reinterpret_cast<ushort4*>(out + (size_t)row * 1024)[t] = r;
}

// ---------------- split GEMM: C[M,N] = (Ah+Al/S)(Bh+Bl/S)^T, f32 out ------------
// MODE 0: plain f32 store. MODE 1: f32 store + residual.
template<int MODE>
__launch_bounds__(256, 2)
__global__ void gemm_split(const f16* __restrict__ Ah_g, const f16* __restrict__ Al_g,
                           const f16* __restrict__ Bh_g, const f16* __restrict__ Bl_g,
                           float* __restrict__ Cf, const float* __restrict__ res,
                           int K, int ldc) {
    __shared__ f16 Ah[128*64], Al[128*64], Bh[128*64], Bl[128*64];
    const int tid = threadIdx.x;
    const int l = tid & 63, w = tid >> 6;
    const int lo = l & 15, hi = l >> 4;
    const int wm = w >> 1, wn = w & 1;
    const int by = blockIdx.y, bx = blockIdx.x;

    f32x4 a0[4][4], a1[4][4];
#pragma unroll
    for (int i = 0; i < 4; ++i)
#pragma unroll
        for (int j = 0; j < 4; ++j) { a0[i][j] = (f32x4)0.f; a1[i][j] = (f32x4)0.f; }

    for (int k0 = 0; k0 < K; k0 += 64) {
#pragma unroll
        for (int i = 0; i < 4; ++i) {
            int Lb = i * 4096 + w * 1024 + l * 16;
            int row = Lb >> 7, cole = (Lb & 127) >> 1;
            size_t ga = (size_t)(by * 128 + row) * K + k0 + cole;
            size_t gb = (size_t)(bx * 128 + row) * K + k0 + cole;
            gload_lds16(Ah_g + ga, (char*)Ah + i * 4096 + w * 1024);
            gload_lds16(Al_g + ga, (char*)Al + i * 4096 + w * 1024);
            gload_lds16(Bh_g + gb, (char*)Bh + i * 4096 + w * 1024);
            gload_lds16(Bl_g + gb, (char*)Bl + i * 4096 + w * 1024);
        }
        __syncthreads();
#pragma unroll
        for (int kk = 0; kk < 2; ++kk) {
            f16x8 ah[4], al[4], bh[4], bl[4];
#pragma unroll
            for (int mi = 0; mi < 4; ++mi) {
                int o = (wm * 64 + mi * 16 + lo) * 128 + kk * 64 + hi * 16;
                ah[mi] = *reinterpret_cast<const f16x8*>((const char*)Ah + o);
                al[mi] = *reinterpret_cast<const f16x8*>((const char*)Al + o);
            }
#pragma unroll
            for (int ni = 0; ni < 4; ++ni) {
                int o = (wn * 64 + ni * 16 + lo) * 128 + kk * 64 + hi * 16;
                bh[ni] = *reinterpret_cast<const f16x8*>((const char*)Bh + o);
                bl[ni] = *reinterpret_cast<const f16x8*>((const char*)Bl + o);
            }
#pragma unroll
            for (int mi = 0; mi < 4; ++mi)
#pragma unroll
                for (int ni = 0; ni < 4; ++ni) {
                    a0[mi][ni] = MFMAH(ah[mi], bh[ni], a0[mi][ni]);
                    a1[mi][ni] = MFMAH(ah[mi], bl[ni], a1[mi][ni]);
                    a1[mi][ni] = MFMAH(al[mi], bh[ni], a1[mi][ni]);
                }
        }
        __syncthreads();
    }
#pragma unroll
    for (int mi = 0; mi < 4; ++mi)
#pragma unroll
        for (int ni = 0; ni < 4; ++ni)
#pragma unroll
            for (int r = 0; r < 4; ++r) {
                int ml = by * 128 + wm * 64 + mi * 16 + hi * 4 + r;
                int nc = bx * 128 + wn * 64 + ni * 16 + lo;
                float v = a0[mi][ni][r] + a1[mi][ni][r] * INV_LO;
                if (MODE == 1) v += res[(size_t)ml * ldc + nc];
                Cf[(size_t)ml * ldc + nc] = v;
            }
}

// ---------------- RoPE cos/sin tables -------------------------------------------
__global__ void rope_tables(float* __restrict__ ct, float* __restrict__ st) {
    int idx = blockIdx.x * 256 + threadIdx.x;
    if (idx >= 2048 * 32) return;
    int s = idx >> 5, i = idx & 31;
    float p32 = (float)pow(10000.0, (double)i * (1.0 / 32.0));
    float freq = 1.0f / p32;
    float ang = (float)s * freq;
    ct[idx] = cosf(ang);
    st[idx] = sinf(ang);
}

// ---------------- RoPE + split on f32 QKV (table-driven) ------------------------
__global__ void rope_split(const float* __restrict__ qkv32,
                           const float* __restrict__ ct, const float* __restrict__ st,
                           f16* __restrict__ QH, f16* __restrict__ QL,
                           f16* __restrict__ KH, f16* __restrict__ KL) {
    int idx = blockIdx.x * 256 + threadIdx.x;
    if (idx >= 2048 * 24 * 32) return;
    int s = idx / 768, r = idx % 768;
    int hh = r >> 5, i = r & 31;
    float c = ct[s * 32 + i], sn = st[s * 32 + i];
    if (hh < 16) {
        const float* p = qkv32 + (size_t)s * 2048 + hh * 64 + i;
        float t1 = p[0], t2 = p[32];
        float v1 = t1 * c - t2 * sn, v2 = t2 * c + t1 * sn;
        size_t base = (size_t)s * 1024 + hh * 64 + i;
        f16 h, l;
        fsplit(v1, h, l); QH[base] = h;      QL[base] = l;
        fsplit(v2, h, l); QH[base + 32] = h; QL[base + 32] = l;
    } else {
        const float* p = qkv32 + (size_t)s * 2048 + 1024 + (hh - 16) * 64 + i;
        float t1 = p[0], t2 = p[32];
        float v1 = t1 * c - t2 * sn, v2 = t2 * c + t1 * sn;
        size_t base = (size_t)s * 512 + (hh - 16) * 64 + i;
        f16 h, l;
        fsplit(v1, h, l); KH[base] = h;      KL[base] = l;
        fsplit(v2, h, l); KH[base + 32] = h; KL[base + 32] = l;
    }
}

// ---------------- V transpose + split: qkv32 v-cols -> vt[512][2048] x2 ---------
__global__ void split_v_t(const float* __restrict__ qkv32,
                          f16* __restrict__ vth, f16* __restrict__ vtl) {
    __shared__ float tile[32][33];
    int c0 = blockIdx.x * 32, s0 = blockIdx.y * 32;
    int tx = threadIdx.x & 31, ty = threadIdx.x >> 5;
#pragma unroll
    for (int i = 0; i < 4; ++i)
        tile[ty + 8*i][tx] = qkv32[(size_t)(s0 + ty + 8*i) * 2048 + 1536 + c0 + tx];
    __syncthreads();
#pragma unroll
    for (int i = 0; i < 4; ++i) {
        float v = tile[tx][ty + 8*i];
        f16 h, l; fsplit(v, h, l);
        size_t o = (size_t)(c0 + ty + 8*i) * 2048 + s0 + tx;
        vth[o] = h; vtl[o] = l;
    }
}

// ---------------- flash attention v3: 4-wave blocks, LDS-staged K/V, split-K ----
__launch_bounds__(256, 4)
__global__ void flash_attn_v3(const f16* __restrict__ QH, const f16* __restrict__ QL,
                              const f16* __restrict__ KH, const f16* __restrict__ KL,
                              const f16* __restrict__ VTH, const f16* __restrict__ VTL,
                              float* __restrict__ PO, float* __restrict__ PS) {
    const int c = blockIdx.x;           // K chunk (512 rows)
    const int qt64 = blockIdx.y;        // 64-row q tile
    const int h = blockIdx.z;
    const int qbase64 = qt64 * 64;
    const int kstart = c * 512;
    const int kend_blk = min(kstart + 512, qbase64 + 64);
    if (kstart >= kend_blk) return;     // uniform early exit
    const int kvh = h >> 1;
    const int tid = threadIdx.x;
    const int w = tid >> 6, l = tid & 63;
    const int lo = l & 15, hi = l >> 4;
    const int qbase = qbase64 + w * 16; // this wave's 16 q-rows
    const int kmax_w = qbase + 16;

    __shared__ f16 KHs[2][32 * 64];
    __shared__ f16 KLs[2][32 * 64];
    __shared__ f16 VHs[2][64 * 32];
    __shared__ f16 VLs[2][64 * 32];

    const f16* qrh = QH + (size_t)(qbase + lo) * 1024 + h * 64;
    const f16* qrl = QL + (size_t)(qbase + lo) * 1024 + h * 64;
    f16x8 qh0 = *reinterpret_cast<const f16x8*>(qrh + hi * 8);
    f16x8 qh1 = *reinterpret_cast<const f16x8*>(qrh + 32 + hi * 8);
    f16x8 ql0 = *reinterpret_cast<const f16x8*>(qrl + hi * 8);
    f16x8 ql1 = *reinterpret_cast<const f16x8*>(qrl + 32 + hi * 8);

    f32x4 o0 = (f32x4)0.f, o1 = (f32x4)0.f, o2 = (f32x4)0.f, o3 = (f32x4)0.f;
    f32x4 c0v = (f32x4)0.f, c1v = (f32x4)0.f, c2v = (f32x4)0.f, c3v = (f32x4)0.f;
    float psum = 0.f;
    const int qg = qbase + lo;
    const int srcA = ((2 * hi) & 3) * 16 + lo;
    const int srcB = ((2 * hi + 1) & 3) * 16 + lo;
    const bool th = (hi >= 2);

    // staging lane mapping (per wave: 1KB each of Kh/Kl/Vh/Vl)
    const int rK = w * 8 + (l >> 3), sK = l & 7;
    const int sKg = sK ^ (rK & 7);
    const int dV = w * 16 + (l >> 2), sV = l & 3;
    const int sVg = sV ^ ((dV >> 1) & 3);
    const f16* KHg = KH + (size_t)rK * 512 + kvh * 64 + sKg * 8;
    const f16* KLg = KL + (size_t)rK * 512 + kvh * 64 + sKg * 8;
    const f16* VHg = VTH + (size_t)(kvh * 64 + dV) * 2048 + sVg * 8;
    const f16* VLg = VTL + (size_t)(kvh * 64 + dV) * 2048 + sVg * 8;

    auto stage = [&](int buf, int kb) {
        gload_lds16(KHg + (size_t)kb * 512, (char*)&KHs[buf][0] + w * 1024);
        gload_lds16(KLg + (size_t)kb * 512, (char*)&KLs[buf][0] + w * 1024);
        gload_lds16(VHg + kb,               (char*)&VHs[buf][0] + w * 1024);
        gload_lds16(VLg + kb,               (char*)&VLs[buf][0] + w * 1024);
    };

    const int swk = lo & 7;
    const int swv = (lo >> 1) & 3;
    const int kA = (hi ^ swk) << 4, kB = ((hi + 4) ^ swk) << 4;
    const int vA = (hi ^ swv) << 4;

    auto stepc = [&](int buf, int kb, bool masked) {
        const char* Kh = (const char*)&KHs[buf][0];
        const char* Kl = (const char*)&KLs[buf][0];
        const char* Vh = (const char*)&VHs[buf][0];
        const char* Vl = (const char*)&VLs[buf][0];
        f16x8 kh00 = *reinterpret_cast<const f16x8*>(Kh + lo * 128 + kA);
        f16x8 kh01 = *reinterpret_cast<const f16x8*>(Kh + lo * 128 + kB);
        f16x8 kl00 = *reinterpret_cast<const f16x8*>(Kl + lo * 128 + kA);
        f16x8 kl01 = *reinterpret_cast<const f16x8*>(Kl + lo * 128 + kB);
        f16x8 kh10 = *reinterpret_cast<const f16x8*>(Kh + (16 + lo) * 128 + kA);
        f16x8 kh11 = *reinterpret_cast<const f16x8*>(Kh + (16 + lo) * 128 + kB);
        f16x8 kl10 = *reinterpret_cast<const f16x8*>(Kl + (16 + lo) * 128 + kA);
        f16x8 kl11 = *reinterpret_cast<const f16x8*>(Kl + (16 + lo) * 128 + kB);
        f32x4 z = (f32x4)0.f;
        f32x4 s0h = MFMAH(kh00, qh0, z);  s0h = MFMAH(kh01, qh1, s0h);
        f32x4 s0c = MFMAH(kh00, ql0, z);  s0c = MFMAH(kh01, ql1, s0c);
        s0c = MFMAH(kl00, qh0, s0c);      s0c = MFMAH(kl01, qh1, s0c);
        f32x4 s1h = MFMAH(kh10, qh0, z);  s1h = MFMAH(kh11, qh1, s1h);
        f32x4 s1c = MFMAH(kh10, ql0, z);  s1c = MFMAH(kh11, ql1, s1c);
        s1c = MFMAH(kl10, qh0, s1c);      s1c = MFMAH(kl11, qh1, s1c);

        float p0[4], p1[4];
#pragma unroll
        for (int r = 0; r < 4; ++r) {
            float v0 = (s0h[r] + s0c[r] * INV_LO) * 0.125f;
            float v1 = (s1h[r] + s1c[r] * INV_LO) * 0.125f;
            p0[r] = __expf(v0);
            p1[r] = __expf(v1);
            if (masked) {
                int kg0 = kb + hi * 4 + r;
                if (kg0 > qg)      p0[r] = 0.f;
                if (kg0 + 16 > qg) p1[r] = 0.f;
            }
            psum += p0[r] + p1[r];
        }

        f16 ph[8], pl[8];
#pragma unroll
        for (int r = 0; r < 4; ++r) {
            fsplit(p0[r], ph[r], pl[r]);
            fsplit(p1[r], ph[4 + r], pl[4 + r]);
        }
        u32 hk00 = packh2(ph[0], ph[1]), hk01 = packh2(ph[2], ph[3]);
        u32 hk10 = packh2(ph[4], ph[5]), hk11 = packh2(ph[6], ph[7]);
        u32 lk00 = packh2(pl[0], pl[1]), lk01 = packh2(pl[2], pl[3]);
        u32 lk10 = packh2(pl[4], pl[5]), lk11 = packh2(pl[6], pl[7]);
        union { u32 u[4]; f16x8 v; } pwh, pwl;
        {
            u32 a00 = __shfl(hk00, srcA), a01 = __shfl(hk01, srcA);
            u32 a10 = __shfl(hk10, srcA), a11 = __shfl(hk11, srcA);
            u32 b00 = __shfl(hk00, srcB), b01 = __shfl(hk01, srcB);
            u32 b10 = __shfl(hk10, srcB), b11 = __shfl(hk11, srcB);
            pwh.u[0] = th ? a10 : a00;
            pwh.u[1] = th ? a11 : a01;
            pwh.u[2] = th ? b10 : b00;
            pwh.u[3] = th ? b11 : b01;
        }
        {
            u32 a00 = __shfl(lk00, srcA), a01 = __shfl(lk01, srcA);
            u32 a10 = __shfl(lk10, srcA), a11 = __shfl(lk11, srcA);
            u32 b00 = __shfl(lk00, srcB), b01 = __shfl(lk01, srcB);
            u32 b10 = __shfl(lk10, srcB), b11 = __shfl(lk11, srcB);
            pwl.u[0] = th ? a10 : a00;
            pwl.u[1] = th ? a11 : a01;
            pwl.u[2] = th ? b10 : b00;
            pwl.u[3] = th ? b11 : b01;
        }
        f16x8 pbh = pwh.v, pbl = pwl.v;

        f16x8 vh0 = *reinterpret_cast<const f16x8*>(Vh + (0 * 16 + lo) * 64 + vA);
        f16x8 vh1 = *reinterpret_cast<const f16x8*>(Vh + (1 * 16 + lo) * 64 + vA);
        f16x8 vh2 = *reinterpret_cast<const f16x8*>(Vh + (2 * 16 + lo) * 64 + vA);
        f16x8 vh3 = *reinterpret_cast<const f16x8*>(Vh + (3 * 16 + lo) * 64 + vA);
        f16x8 vl0 = *reinterpret_cast<const f16x8*>(Vl + (0 * 16 + lo) * 64 + vA);
        f16x8 vl1 = *reinterpret_cast<const f16x8*>(Vl + (1 * 16 + lo) * 64 + vA);
        f16x8 vl2 = *reinterpret_cast<const f16x8*>(Vl + (2 * 16 + lo) * 64 + vA);
        f16x8 vl3 = *reinterpret_cast<const f16x8*>(Vl + (3 * 16 + lo) * 64 + vA);
        o0 = MFMAH(vh0, pbh, o0);
        o1 = MFMAH(vh1, pbh, o1);
        o2 = MFMAH(vh2, pbh, o2);
        o3 = MFMAH(vh3, pbh, o3);
        c0v = MFMAH(vh0, pbl, c0v);  c0v = MFMAH(vl0, pbh, c0v);
        c1v = MFMAH(vh1, pbl, c1v);  c1v = MFMAH(vl1, pbh, c1v);
        c2v = MFMAH(vh2, pbl, c2v);  c2v = MFMAH(vl2, pbh, c2v);
        c3v = MFMAH(vh3, pbl, c3v);  c3v = MFMAH(vl3, pbh, c3v);
    };

    int buf = 0;
    stage(0, kstart);
    for (int kb = kstart; kb < kend_blk; kb += 32) {
        __syncthreads();                       // staged buf ready (vmcnt drained)
        if (kb + 32 < kend_blk) stage(buf ^ 1, kb + 32);
        if (kb < kmax_w)
            stepc(buf, kb, kb + 32 > qbase);
        buf ^= 1;
    }

    if (kstart < kmax_w) {
        float ls = psum;
        ls += __shfl_xor(ls, 16);
        ls += __shfl_xor(ls, 32);
        const int qt16 = qt64 * 4 + w;
        const size_t slot = ((size_t)(h * 128 + qt16) * 4 + c);
        float* po = PO + slot * 1024;
#pragma unroll
        for (int r = 0; r < 4; ++r) {
            po[lo * 64 + 0  + hi * 4 + r] = o0[r] + c0v[r] * INV_LO;
            po[lo * 64 + 16 + hi * 4 + r] = o1[r] + c1v[r] * INV_LO;
            po[lo * 64 + 32 + hi * 4 + r] = o2[r] + c2v[r] * INV_LO;
            po[lo * 64 + 48 + hi * 4 + r] = o3[r] + c3v[r] * INV_LO;
        }
        if (l < 16) PS[slot * 16 + lo] = ls;
    }
}

// ---------------- combine split-K partials -> split-f16 ATTN --------------------
__global__ void attn_combine(const float* __restrict__ PO, const float* __restrict__ PS,
                             f16* __restrict__ AH, f16* __restrict__ AL) {
    const int s = blockIdx.x, t = threadIdx.x;   // s: token row, t*4: dim
    const int qt = s >> 4, r = s & 15;
    const int nc = (qt * 16 + 16 + 511) >> 9;
    const int d0 = t * 4;
    const int h = d0 >> 6;
    const size_t sbase = (size_t)(h * 128 + qt) * 4;
    float4 acc = make_float4(0.f, 0.f, 0.f, 0.f);
    float ps = 0.f;
    for (int c = 0; c < nc; ++c) {
        const float4 v = *reinterpret_cast<const float4*>(
            PO + (sbase + c) * 1024 + r * 64 + (d0 & 63));
        acc.x += v.x; acc.y += v.y; acc.z += v.z; acc.w += v.w;
        ps += PS[(sbase + c) * 16 + r];
    }
    float inv = 1.f / ps;
    union { f16 f[4]; ushort4 u; } H, L;
    fsplit(acc.x * inv, H.f[0], L.f[0]);
    fsplit(acc.y * inv, H.f[1], L.f[1]);
    fsplit(acc.z * inv, H.f[2], L.f[2]);
    fsplit(acc.w * inv, H.f[3], L.f[3]);
    reinterpret_cast<ushort4*>((u16*)AH + (size_t)s * 1024)[t] = H.u;
    reinterpret_cast<ushort4*>((u16*)AL + (size_t)s * 1024)[t] = L.u;
}

// ---------------- MoE up-projection: BM=256, BN=128 (w1/w3 interleaved) ---------
// bx in [0,44): each block covers W13T rows [bx*128, bx*128+128) = 64 output
// features. Silu fuse intra-thread. 3 blocks/CU residency (144KB LDS).
__launch_bounds__(256, 3)
__global__ void moe_up(const u16* __restrict__ A, const u16* __restrict__ B13,
                       u16* __restrict__ ACT,
                       const int* __restrict__ e_cnt, const int* __restrict__ e_off,
                       const int* __restrict__ glist) {
    const int e = blockIdx.z;
    const int Me = e_cnt[e], off = e_off[e];
    const int by = blockIdx.y, bx = blockIdx.x;   // bx in [0,44)
    if (by * 256 >= Me) return;
    const u16* Be = B13 + (size_t)e * 5632 * 1024;

    __shared__ u16 As[256 * 64];
    __shared__ u16 Bs[128 * 64];

    const int tid = threadIdx.x;
    const int l = tid & 63, w = tid >> 6;
    const int lo = l & 15, hi = l >> 4;

    f32x4 acc[4][8];
#pragma unroll
    for (int i = 0; i < 4; ++i)
#pragma unroll
        for (int j = 0; j < 8; ++j) acc[i][j] = (f32x4)0.f;

    const int srow = tid >> 3;          // 0..31 within each 32-row group
    const int colb = (tid & 7) * 16;    // byte col within 128B row
    int arow[8];
#pragma unroll
    for (int i = 0; i < 8; ++i) {
        int ml = by * 256 + i * 32 + srow;
        if (ml > Me - 1) ml = Me - 1;
        arow[i] = glist[off + ml];
    }
    const int brow = bx * 128 + srow;

    for (int k0 = 0; k0 < 1024; k0 += 64) {
#pragma unroll
        for (int i = 0; i < 8; ++i)
            gload_lds16(A + (size_t)arow[i] * 1024 + k0 + (colb >> 1),
                        (char*)As + i * 4096 + w * 1024);
#pragma unroll
        for (int i = 0; i < 4; ++i)
            gload_lds16(Be + (size_t)(brow + i * 32) * 1024 + k0 + (colb >> 1),
                        (char*)Bs + i * 4096 + w * 1024);
        __syncthreads();
#pragma unroll
        for (int kk = 0; kk < 2; ++kk) {
            bf16x8 af[4], bf[8];
#pragma unroll
            for (int mi = 0; mi < 4; ++mi)
                af[mi] = *reinterpret_cast<const bf16x8*>(
                    (const char*)As + (w * 64 + mi * 16 + lo) * 128 + kk * 64 + hi * 16);
#pragma unroll
            for (int ni = 0; ni < 8; ++ni)
                bf[ni] = *reinterpret_cast<const bf16x8*>(
                    (const char*)Bs + (ni * 16 + lo) * 128 + kk * 64 + hi * 16);
#pragma unroll
            for (int mi = 0; mi < 4; ++mi)
#pragma unroll
                for (int ni = 0; ni < 8; ++ni)
                    acc[mi][ni] = MFMAB(af[mi], bf[ni], acc[mi][ni]);
        }
        __syncthreads();
    }
#pragma unroll
    for (int mi = 0; mi < 4; ++mi)
#pragma unroll
        for (int ni = 0; ni < 4; ++ni)
#pragma unroll
            for (int r = 0; r < 4; ++r) {
                int ml = by * 256 + w * 64 + mi * 16 + hi * 4 + r;
                if (ml < Me) {
                    int nc = bx * 64 + ni * 16 + lo;
                    float hh = acc[mi][ni][r], gg = acc[mi][ni + 4][r];
                    float sg = hh / (1.f + __expf(-hh));
                    ACT[(size_t)(off + ml) * 2816 + nc] = f2bf(sg * gg);
                }
            }
}

// ---------------- MoE down-projection: BM=256, BN=128, SPLIT-K x4 ---------------
// 4 waves as 2M x 2N, wave-tile 128x64 (MR=8, NR=4). 3 blocks/CU residency.
// blockIdx.x = bx (0..7) | ks<<3 (0..3); K chunk = [ks*704, ks*704+704).
__launch_bounds__(256, 3)
__global__ void moe_down(const u16* __restrict__ ACT, const u16* __restrict__ B2,
                         float* __restrict__ YP,
                         const int* __restrict__ e_cnt, const int* __restrict__ e_off) {
    const int e = blockIdx.z;
    const int Me = e_cnt[e], off = e_off[e];
    const int by = blockIdx.y;
    const int bx = blockIdx.x & 7;
    const int ks = blockIdx.x >> 3;
    if (by * 256 >= Me) return;
    const u16* Be = B2 + (size_t)e * 1024 * 2816;

    __shared__ u16 As[256 * 64];
    __shared__ u16 Bs[128 * 64];

    const int tid = threadIdx.x;
    const int l = tid & 63, w = tid >> 6;
    const int lo = l & 15, hi = l >> 4;
    const int wm = w >> 1, wn = w & 1;

    f32x4 acc[8][4];
#pragma unroll
    for (int i = 0; i < 8; ++i)
#pragma unroll
        for (int j = 0; j < 4; ++j) acc[i][j] = (f32x4)0.f;

    const int srow = tid >> 3;
    const int colb = (tid & 7) * 16;
    int amrow[8];
#pragma unroll
    for (int i = 0; i < 8; ++i) {
        int ml = by * 256 + i * 32 + srow;
        if (ml > Me - 1) ml = Me - 1;
        amrow[i] = off + ml;
    }
    const int brow = bx * 128 + srow;

    const int kbeg = ks * 704, kend = kbeg + 704;
    for (int k0 = kbeg; k0 < kend; k0 += 64) {
#pragma unroll
        for (int i = 0; i < 8; ++i)
            gload_lds16(ACT + (size_t)amrow[i] * 2816 + k0 + (colb >> 1),
                        (char*)As + i * 4096 + w * 1024);
#pragma unroll
        for (int i = 0; i < 4; ++i)
            gload_lds16(Be + (size_t)(brow + i * 32) * 2816 + k0 + (colb >> 1),
                        (char*)Bs + i * 4096 + w * 1024);
        __syncthreads();
#pragma unroll
        for (int kk = 0; kk < 2; ++kk) {
            bf16x8 af[8], bf[4];
#pragma unroll
            for (int mi = 0; mi < 8; ++mi)
                af[mi] = *reinterpret_cast<const bf16x8*>(
                    (const char*)As + (wm * 128 + mi * 16 + lo) * 128 + kk * 64 + hi * 16);
#pragma unroll
            for (int ni = 0; ni < 4; ++ni)
                bf[ni] = *reinterpret_cast<const bf16x8*>(
                    (const char*)Bs + (wn * 64 + ni * 16 + lo) * 128 + kk * 64 + hi * 16);
#pragma unroll
            for (int mi = 0; mi < 8; ++mi)
#pragma unroll
                for (int ni = 0; ni < 4; ++ni)
                    acc[mi][ni] = MFMAB(af[mi], bf[ni], acc[mi][ni]);
        }
        __syncthreads();
    }
    float* Yk = YP + (size_t)ks * YSTR;
#pragma unroll
    for (int mi = 0; mi < 8; ++mi)
#pragma unroll
        for (int ni = 0; ni < 4; ++ni)
#pragma unroll
            for (int r = 0; r < 4; ++r) {
                int ml = by * 256 + wm * 128 + mi * 16 + hi * 4 + r;
                if (ml < Me) {
                    int nc = bx * 128 + wn * 64 + ni * 16 + lo;
                    Yk[(size_t)(off + ml) * 1024 + nc] = acc[mi][ni][r];
                }
            }
}

// ---------------- router (full f32, 1 wave / token) -----------------------------
__global__ void router_kernel(const float* __restrict__ x2, const float* __restrict__ ln2w,
                              const float* __restrict__ wr,
                              int* __restrict__ topi, float* __restrict__ topw) {
    const int t = blockIdx.x, l = threadIdx.x;
    float ss = 0.f;
    float acc[8] = {0.f,0.f,0.f,0.f,0.f,0.f,0.f,0.f};
    const float* xr = x2 + (size_t)t * 1024;
    for (int d = l; d < 1024; d += 64) {
        float xv = xr[d];
        ss += xv * xv;
        float xw = xv * ln2w[d];
        const float* wrow = wr + (size_t)d * 8;
#pragma unroll
        for (int e2 = 0; e2 < 8; ++e2) acc[e2] += xw * wrow[e2];
    }
#pragma unroll
    for (int o = 32; o >= 1; o >>= 1) {
        ss += __shfl_xor(ss, o);
#pragma unroll
        for (int e2 = 0; e2 < 8; ++e2) acc[e2] += __shfl_xor(acc[e2], o);
    }
    if (l == 0) {
        float inv = rsqrtf(ss * (1.f/1024.f) + 1e-6f);
        float pe[8]; float mx = -3e38f;
#pragma unroll
        for (int e2 = 0; e2 < 8; ++e2) { pe[e2] = acc[e2] * inv; mx = fmaxf(mx, pe[e2]); }
#pragma unroll
        for (int e2 = 0; e2 < 8; ++e2) pe[e2] = expf(pe[e2] - mx);
        int i0 = 0; float b0 = -1.f;
#pragma unroll
        for (int e2 = 0; e2 < 8; ++e2) if (pe[e2] > b0) { b0 = pe[e2]; i0 = e2; }
        int i1 = -1; float b1 = -1.f;
#pragma unroll
        for (int e2 = 0; e2 < 8; ++e2) if (e2 != i0 && pe[e2] > b1) { b1 = pe[e2]; i1 = e2; }
        float wsum = b0 + b1;
        topi[2*t] = i0;  topi[2*t+1] = i1;
        topw[2*t] = b0 / wsum;  topw[2*t+1] = b1 / wsum;
    }
}

__global__ void moe_count(const int* __restrict__ topi, int* __restrict__ cnt) {
    __shared__ int lh[8];
    int t = threadIdx.x;
    if (t < 8) lh[t] = 0;
    __syncthreads();
    int tok = blockIdx.x * 256 + t;
    if (tok < 2048) {
        atomicAdd(&lh[topi[2*tok]], 1);
        atomicAdd(&lh[topi[2*tok+1]], 1);
    }
    __syncthreads();
    if (t < 8) atomicAdd(&cnt[t], lh[t]);
}

__global__ void moe_offsets(const int* __restrict__ cnt, int* __restrict__ offp) {
    if (threadIdx.x == 0 && blockIdx.x == 0) {
        int s = 0;
        for (int e2 = 0; e2 < 8; ++e2) { offp[e2] = s; s += cnt[e2]; }
    }
}

__global__ void moe_assign(const int* __restrict__ topi, const int* __restrict__ offp,
                           int* __restrict__ cur, int* __restrict__ tok_of,
                           int* __restrict__ slot_of) {
    int tok = blockIdx.x * 256 + threadIdx.x;
    if (tok < 2048) {
#pragma unroll
        for (int j = 0; j < 2; ++j) {
            int e2 = topi[2*tok + j];
            int s = atomicAdd(&cur[e2], 1);
            int g = offp[e2] + s;
            tok_of[g] = tok;
            slot_of[2*tok + j] = g;
        }
    }
}

// sums 4 split-K partials per slot (fixed order -> deterministic)
__global__ void combine_kernel(const float* __restrict__ x2, const float* __restrict__ yp,
                               const int* __restrict__ slot_of, const float* __restrict__ topw,
                               float* __restrict__ outp) {
    int t = blockIdx.x, i = threadIdx.x;
    int s0 = slot_of[2*t], s1 = slot_of[2*t+1];
    float w0 = topw[2*t], w1 = topw[2*t+1];
    float4 a = reinterpret_cast<const float4*>(x2 + (size_t)t * 1024)[i];
    float4 y0 = make_float4(0.f, 0.f, 0.f, 0.f);
    float4 y1 = make_float4(0.f, 0.f, 0.f, 0.f);
#pragma unroll
    for (int ks = 0; ks < 4; ++ks) {
        const float4 v0 = reinterpret_cast<const float4*>(yp + ks * YSTR + (size_t)s0 * 1024)[i];
        const float4 v1 = reinterpret_cast<const float4*>(yp + ks * YSTR + (size_t)s1 * 1024)[i];
        y0.x += v0.x; y0.y += v0.y; y0.z += v0.z; y0.w += v0.w;
        y1.x += v1.x; y1.y += v1.y; y1.z += v1.z; y1.w += v1.w;
    }
    float4 r;
    r.x = a.x + w0 * y0.x + w1 * y1.x;
    r.y = a.y + w0 * y0.y + w1 * y1.y;
    r.z = a.z + w0 * y0.z + w1 * y1.z;
    r.w = a.w + w0 * y0.w + w1 * y1.w;
    reinterpret_cast<float4*>(outp + (size_t)t * 1024)[i] = r;
}

// ================================================================================
extern "C" void kernel_launch(void* const* d_in, const int* in_sizes, int n_in,
                              void* d_out, int out_size, void* d_ws, size_t ws_size,
                              hipStream_t stream) {
    (void)in_sizes; (void)n_in; (void)out_size; (void)ws_size;
    const float* x    = (const float*)d_in[0];
    const float* ln1w = (const float*)d_in[3];
    const float* wq   = (const float*)d_in[4];
    const float* wk   = (const float*)d_in[5];
    const float* wv   = (const float*)d_in[6];
    const float* wo   = (const float*)d_in[7];
    const float* ln2w = (const float*)d_in[8];
    const float* wr   = (const float*)d_in[9];
    const float* w1   = (const float*)d_in[10];
    const float* w3   = (const float*)d_in[11];
    const float* w2   = (const float*)d_in[12];
    float* outp = (float*)d_out;

    char* ws = (char*)d_ws;
    size_t off = 0;
    auto alloc = [&](size_t bytes) -> char* {
        char* p = ws + off;
        off += (bytes + 255) & ~(size_t)255;
        return p;
    };
    // persistent weights (split f16 attention, bf16 MoE)
    f16* WQKVTH = (f16*)alloc(2048ull * 1024 * 2);
    f16* WQKVTL = (f16*)alloc(2048ull * 1024 * 2);
    f16* WOTH   = (f16*)alloc(1024ull * 1024 * 2);
    f16* WOTL   = (f16*)alloc(1024ull * 1024 * 2);
    u16* W13T   = (u16*)alloc(8ull * 5632 * 1024 * 2);   // w1/w3 interleaved
    u16* W2T    = (u16*)alloc(8ull * 1024 * 2816 * 2);
    // persistent activations
    float* X2   = (float*)alloc(2048ull * 1024 * 4);
    u16*  XN2   = (u16*)alloc(2048ull * 1024 * 2);
    float* CT   = (float*)alloc(2048ull * 32 * 4);
    float* ST   = (float*)alloc(2048ull * 32 * 4);
    int*  TOPI  = (int*)alloc(2048 * 2 * 4);
    float* TOPW = (float*)alloc(2048 * 2 * 4);
    int*  SLOT  = (int*)alloc(2048 * 2 * 4);
    int*  TOK   = (int*)alloc(4224 * 4);
    int*  CNT   = (int*)alloc(8 * 4);
    int*  CUR   = (int*)alloc(8 * 4);
    int*  OFFP  = (int*)alloc(8 * 4);
    // aliased arena: attention temps, then MoE temps
    size_t arena_start = off;
    f16* XN1H = (f16*)alloc(2048ull * 1024 * 2);
    f16* XN1L = (f16*)alloc(2048ull * 1024 * 2);
    float* QKV32 = (float*)alloc(2048ull * 2048 * 4);
    f16* QH = (f16*)alloc(2048ull * 1024 * 2);
    f16* QL = (f16*)alloc(2048ull * 1024 * 2);
    f16* KH = (f16*)alloc(2048ull * 512 * 2);
    f16* KL = (f16*)alloc(2048ull * 512 * 2);
    f16* VTH = (f16*)alloc(512ull * 2048 * 2);
    f16* VTL = (f16*)alloc(512ull * 2048 * 2);
    f16* ATTNH = (f16*)alloc(2048ull * 1024 * 2);
    f16* ATTNL = (f16*)alloc(2048ull * 1024 * 2);
    float* PO  = (float*)alloc(8192ull * 1024 * 4);   // split-K partial O
    float* PS  = (float*)alloc(8192ull * 16 * 4);     // split-K partial psum
    size_t arena_end_attn = off;
    // MoE arena aliases the attention arena
    off = arena_start;
    u16*  ACT = (u16*)alloc((4096ull + 256) * 2816 * 2);
    float* YP = (float*)alloc(4ull * YSTR * 4);       // 4 split-K partial Y buffers
    if (off < arena_end_attn) off = arena_end_attn;

    hipMemsetAsync(CNT, 0, 32, stream);
    hipMemsetAsync(CUR, 0, 32, stream);

    dim3 tb(256);
    // weight prep
    transpose_wsplit<<<dim3(32, 32), tb, 0, stream>>>(wq, WQKVTH, WQKVTL, 1024, 1024);
    transpose_wsplit<<<dim3(16, 32), tb, 0, stream>>>(wk, WQKVTH + 1024ull*1024, WQKVTL + 1024ull*1024, 1024, 512);
    transpose_wsplit<<<dim3(16, 32), tb, 0, stream>>>(wv, WQKVTH + 1536ull*1024, WQKVTL + 1536ull*1024, 1024, 512);
    transpose_wsplit<<<dim3(32, 32), tb, 0, stream>>>(wo, WOTH, WOTL, 1024, 1024);
    transpose_w13<<<dim3(88, 32, 8), tb, 0, stream>>>(w1, W13T, 0);
    transpose_w13<<<dim3(88, 32, 8), tb, 0, stream>>>(w3, W13T, 64);
    transpose_wb<<<dim3(32, 88, 8), tb, 0, stream>>>(w2, W2T, 2816, 1024);

    rope_tables<<<dim3((2048 * 32 + 255) / 256), tb, 0, stream>>>(CT, ST);
    rmsnorm_split<<<dim3(2048), tb, 0, stream>>>(x, ln1w, XN1H, XN1L);

    // QKV projection (split precision, f32 out)
    gemm_split<0><<<dim3(16, 16), tb, 0, stream>>>(
        XN1H, XN1L, WQKVTH, WQKVTL, QKV32, nullptr, 1024, 2048);

    rope_split<<<dim3((2048 * 768 + 255) / 256), tb, 0, stream>>>(QKV32, CT, ST, QH, QL, KH, KL);
    split_v_t<<<dim3(16, 64), tb, 0, stream>>>(QKV32, VTH, VTL);

    // LDS-staged split-K flash attention + combine
    flash_attn_v3<<<dim3(4, 32, 16), tb, 0, stream>>>(
        QH, QL, KH, KL, VTH, VTL, PO, PS);
    attn_combine<<<dim3(2048), tb, 0, stream>>>(PO, PS, ATTNH, ATTNL);

    // output projection + residual -> X2 (f32)
    gemm_split<1><<<dim3(8, 16), tb, 0, stream>>>(
        ATTNH, ATTNL, WOTH, WOTL, X2, x, 1024, 1024);

    router_kernel<<<dim3(2048), dim3(64), 0, stream>>>(X2, ln2w, wr, TOPI, TOPW);
    rmsnorm_bf16<<<dim3(2048), tb, 0, stream>>>(X2, ln2w, XN2);
    moe_count<<<dim3(8), tb, 0, stream>>>(TOPI, CNT);
    moe_offsets<<<dim3(1), dim3(64), 0, stream>>>(CNT, OFFP);
    moe_assign<<<dim3(8), tb, 0, stream>>>(TOPI, OFFP, CUR, TOK, SLOT);

    // MoE up-projection, BM=256 x BN=128 (interleaved w1/w3), bx in [0,44)
    moe_up<<<dim3(44, 8, 8), tb, 0, stream>>>(
        XN2, W13T, ACT, CNT, OFFP, TOK);

    // MoE down-projection, BM=256 x BN=128, split-K x4
    moe_down<<<dim3(32, 8, 8), tb, 0, stream>>>(
        ACT, W2T, YP, CNT, OFFP);

    combine_kernel<<<dim3(2048), tb, 0, stream>>>(X2, YP, SLOT, TOPW, outp);
}

// Round 14
// 490.334 us; speedup vs baseline: 1.8012x; 1.8012x over previous
//
#include <hip/hip_runtime.h>
#include <hip/hip_bf16.h>
#include <cstdint>

typedef unsigned short u16;
typedef unsigned int   u32;
typedef _Float16 f16;
typedef __bf16    bf16x8 __attribute__((ext_vector_type(8)));
typedef _Float16  f16x8  __attribute__((ext_vector_type(8)));
typedef float     f32x4  __attribute__((ext_vector_type(4)));

#define MFMAB(a,b,c) __builtin_amdgcn_mfma_f32_16x16x32_bf16((a),(b),(c),0,0,0)
#define MFMAH(a,b,c) __builtin_amdgcn_mfma_f32_16x16x32_f16((a),(b),(c),0,0,0)

#define LO_SCALE 4096.0f
#define INV_LO   (1.0f/4096.0f)
#define YSTR (4352ull * 1024ull)

__device__ __forceinline__ float bf2f(u16 u) {
    union { unsigned int i; float f; } c; c.i = ((unsigned int)u) << 16; return c.f;
}
__device__ __forceinline__ u16 f2bf(float f) {
    __bf16 b = (__bf16)f;
    return __builtin_bit_cast(unsigned short, b);
}
__device__ __forceinline__ void fsplit(float v, f16& h, f16& l) {
    f16 hh = (f16)v;
    h = hh;
    l = (f16)((v - (float)hh) * LO_SCALE);
}
__device__ __forceinline__ u32 packh2(f16 a, f16 b) {
    u32 x = (u32)__builtin_bit_cast(u16, a);
    u32 y = (u32)__builtin_bit_cast(u16, b);
    return x | (y << 16);
}
__device__ __forceinline__ void gload_lds16(const void* g, void* l) {
    __builtin_amdgcn_global_load_lds(
        (const __attribute__((address_space(1))) void*)g,
        (__attribute__((address_space(3))) void*)l, 16, 0, 0);
}

// ---------------- weight transpose f32[R][C] -> bf16 [C][R], batched over z -----
__global__ void transpose_wb(const float* __restrict__ in, u16* __restrict__ out,
                             int R, int C) {
    __shared__ float tile[32][33];
    const size_t zb = (size_t)blockIdx.z * (size_t)R * (size_t)C;
    in  += zb; out += zb;
    int c0 = blockIdx.x * 32, r0 = blockIdx.y * 32;
    int tx = threadIdx.x & 31, ty = threadIdx.x >> 5;  // 256 threads: 32x8
#pragma unroll
    for (int i = 0; i < 4; ++i)
        tile[ty + 8*i][tx] = in[(size_t)(r0 + ty + 8*i) * C + c0 + tx];
    __syncthreads();
#pragma unroll
    for (int i = 0; i < 4; ++i)
        out[(size_t)(c0 + ty + 8*i) * R + r0 + tx] = f2bf(tile[tx][ty + 8*i]);
}

// ---------------- weight transpose f32[R][C] -> f16 split [C][R] x2 -------------
__global__ void transpose_wsplit(const float* __restrict__ in, f16* __restrict__ oh,
                                 f16* __restrict__ ol, int R, int C) {
    __shared__ float tile[32][33];
    int c0 = blockIdx.x * 32, r0 = blockIdx.y * 32;
    int tx = threadIdx.x & 31, ty = threadIdx.x >> 5;
#pragma unroll
    for (int i = 0; i < 4; ++i)
        tile[ty + 8*i][tx] = in[(size_t)(r0 + ty + 8*i) * C + c0 + tx];
    __syncthreads();
#pragma unroll
    for (int i = 0; i < 4; ++i) {
        float v = tile[tx][ty + 8*i];
        f16 h, l; fsplit(v, h, l);
        size_t o = (size_t)(c0 + ty + 8*i) * R + r0 + tx;
        oh[o] = h; ol[o] = l;
    }
}

// ---------------- w1/w3 interleaved transpose: f32[1024][2816] -> bf16 W13T -----
// out row for col j: (j>>6)*128 + (j&63) + gofs  (gofs=0 for w1, 64 for w3)
__global__ void transpose_w13(const float* __restrict__ in, u16* __restrict__ out,
                              int gofs) {
    __shared__ float tile[32][33];
    in  += (size_t)blockIdx.z * 1024 * 2816;
    u16* oute = out + (size_t)blockIdx.z * 5632 * 1024;
    int c0 = blockIdx.x * 32, r0 = blockIdx.y * 32;
    int tx = threadIdx.x & 31, ty = threadIdx.x >> 5;
#pragma unroll
    for (int i = 0; i < 4; ++i)
        tile[ty + 8*i][tx] = in[(size_t)(r0 + ty + 8*i) * 2816 + c0 + tx];
    __syncthreads();
#pragma unroll
    for (int i = 0; i < 4; ++i) {
        int cc = c0 + ty + 8*i;
        int orow = ((cc >> 6) << 7) + (cc & 63) + gofs;
        oute[(size_t)orow * 1024 + r0 + tx] = f2bf(tile[tx][ty + 8*i]);
    }
}

// ---------------- RMSNorm f32 -> f16 split (d = 1024, 256 thr/row) --------------
__global__ void rmsnorm_split(const float* __restrict__ x, const float* __restrict__ wt,
                              f16* __restrict__ oh, f16* __restrict__ ol) {
    const int row = blockIdx.x, t = threadIdx.x;
    const float4 xv = reinterpret_cast<const float4*>(x + (size_t)row * 1024)[t];
    float ss = xv.x*xv.x + xv.y*xv.y + xv.z*xv.z + xv.w*xv.w;
#pragma unroll
    for (int o = 32; o >= 1; o >>= 1) ss += __shfl_xor(ss, o);
    __shared__ float red[4];
    if ((t & 63) == 0) red[t >> 6] = ss;
    __syncthreads();
    float tot = red[0] + red[1] + red[2] + red[3];
    float inv = rsqrtf(tot * (1.f/1024.f) + 1e-6f);
    const float4 wv = reinterpret_cast<const float4*>(wt)[t];
    float v[4] = { xv.x*inv*wv.x, xv.y*inv*wv.y, xv.z*inv*wv.z, xv.w*inv*wv.w };
    union { f16 f[4]; ushort4 u; } H, L;
#pragma unroll
    for (int j = 0; j < 4; ++j) fsplit(v[j], H.f[j], L.f[j]);
    reinterpret_cast<ushort4*>((u16*)oh + (size_t)row * 1024)[t] = H.u;
    reinterpret_cast<ushort4*>((u16*)ol + (size_t)row * 1024)[t] = L.u;
}

// ---------------- RMSNorm f32 -> bf16 (for MoE input) ---------------------------
__global__ void rmsnorm_bf16(const float* __restrict__ x, const float* __restrict__ wt,
                             u16* __restrict__ out) {
    const int row = blockIdx.x, t = threadIdx.x;
    const float4 xv = reinterpret_cast<const float4*>(x + (size_t)row * 1024)[t];
    float ss = xv.x*xv.x + xv.y*xv.y + xv.z*xv.z + xv.w*xv.w;
#pragma unroll
    for (int o = 32; o >= 1; o >>= 1) ss += __shfl_xor(ss, o);
    __shared__ float red[4];
    if ((t & 63) == 0) red[t >> 6] = ss;
    __syncthreads();
    float tot = red[0] + red[1] + red[2] + red[3];
    float inv = rsqrtf(tot * (1.f/1024.f) + 1e-6f);
    const float4 wv = reinterpret_cast<const float4*>(wt)[t];
    ushort4 r;
    r.x = f2bf(xv.x * inv * wv.x);
    r.y = f2bf(xv.y * inv * wv.y);
    r.z = f2bf(xv.z * inv * wv.z);
    r.w = f2bf(xv.w * inv * wv.w);
    reinterpret_cast<ushort4*>(out + (size_t)row * 1024)[t] = r;
}

// ---------------- split GEMM: C[M,N] = (Ah+Al/S)(Bh+Bl/S)^T, f32 out ------------
// MODE 0: plain f32 store. MODE 1: f32 store + residual.
template<int MODE>
__launch_bounds__(256, 2)
__global__ void gemm_split(const f16* __restrict__ Ah_g, const f16* __restrict__ Al_g,
                           const f16* __restrict__ Bh_g, const f16* __restrict__ Bl_g,
                           float* __restrict__ Cf, const float* __restrict__ res,
                           int K, int ldc) {
    __shared__ f16 Ah[128*64], Al[128*64], Bh[128*64], Bl[128*64];
    const int tid = threadIdx.x;
    const int l = tid & 63, w = tid >> 6;
    const int lo = l & 15, hi = l >> 4;
    const int wm = w >> 1, wn = w & 1;
    const int by = blockIdx.y, bx = blockIdx.x;

    f32x4 a0[4][4], a1[4][4];
#pragma unroll
    for (int i = 0; i < 4; ++i)
#pragma unroll
        for (int j = 0; j < 4; ++j) { a0[i][j] = (f32x4)0.f; a1[i][j] = (f32x4)0.f; }

    for (int k0 = 0; k0 < K; k0 += 64) {
#pragma unroll
        for (int i = 0; i < 4; ++i) {
            int Lb = i * 4096 + w * 1024 + l * 16;
            int row = Lb >> 7, cole = (Lb & 127) >> 1;
            size_t ga = (size_t)(by * 128 + row) * K + k0 + cole;
            size_t gb = (size_t)(bx * 128 + row) * K + k0 + cole;
            gload_lds16(Ah_g + ga, (char*)Ah + i * 4096 + w * 1024);
            gload_lds16(Al_g + ga, (char*)Al + i * 4096 + w * 1024);
            gload_lds16(Bh_g + gb, (char*)Bh + i * 4096 + w * 1024);
            gload_lds16(Bl_g + gb, (char*)Bl + i * 4096 + w * 1024);
        }
        __syncthreads();
#pragma unroll
        for (int kk = 0; kk < 2; ++kk) {
            f16x8 ah[4], al[4], bh[4], bl[4];
#pragma unroll
            for (int mi = 0; mi < 4; ++mi) {
                int o = (wm * 64 + mi * 16 + lo) * 128 + kk * 64 + hi * 16;
                ah[mi] = *reinterpret_cast<const f16x8*>((const char*)Ah + o);
                al[mi] = *reinterpret_cast<const f16x8*>((const char*)Al + o);
            }
#pragma unroll
            for (int ni = 0; ni < 4; ++ni) {
                int o = (wn * 64 + ni * 16 + lo) * 128 + kk * 64 + hi * 16;
                bh[ni] = *reinterpret_cast<const f16x8*>((const char*)Bh + o);
                bl[ni] = *reinterpret_cast<const f16x8*>((const char*)Bl + o);
            }
#pragma unroll
            for (int mi = 0; mi < 4; ++mi)
#pragma unroll
                for (int ni = 0; ni < 4; ++ni) {
                    a0[mi][ni] = MFMAH(ah[mi], bh[ni], a0[mi][ni]);
                    a1[mi][ni] = MFMAH(ah[mi], bl[ni], a1[mi][ni]);
                    a1[mi][ni] = MFMAH(al[mi], bh[ni], a1[mi][ni]);
                }
        }
        __syncthreads();
    }
#pragma unroll
    for (int mi = 0; mi < 4; ++mi)
#pragma unroll
        for (int ni = 0; ni < 4; ++ni)
#pragma unroll
            for (int r = 0; r < 4; ++r) {
                int ml = by * 128 + wm * 64 + mi * 16 + hi * 4 + r;
                int nc = bx * 128 + wn * 64 + ni * 16 + lo;
                float v = a0[mi][ni][r] + a1[mi][ni][r] * INV_LO;
                if (MODE == 1) v += res[(size_t)ml * ldc + nc];
                Cf[(size_t)ml * ldc + nc] = v;
            }
}

// ---------------- RoPE cos/sin tables -------------------------------------------
__global__ void rope_tables(float* __restrict__ ct, float* __restrict__ st) {
    int idx = blockIdx.x * 256 + threadIdx.x;
    if (idx >= 2048 * 32) return;
    int s = idx >> 5, i = idx & 31;
    float p32 = (float)pow(10000.0, (double)i * (1.0 / 32.0));
    float freq = 1.0f / p32;
    float ang = (float)s * freq;
    ct[idx] = cosf(ang);
    st[idx] = sinf(ang);
}

// ---------------- RoPE + split on f32 QKV (table-driven) ------------------------
__global__ void rope_split(const float* __restrict__ qkv32,
                           const float* __restrict__ ct, const float* __restrict__ st,
                           f16* __restrict__ QH, f16* __restrict__ QL,
                           f16* __restrict__ KH, f16* __restrict__ KL) {
    int idx = blockIdx.x * 256 + threadIdx.x;
    if (idx >= 2048 * 24 * 32) return;
    int s = idx / 768, r = idx % 768;
    int hh = r >> 5, i = r & 31;
    float c = ct[s * 32 + i], sn = st[s * 32 + i];
    if (hh < 16) {
        const float* p = qkv32 + (size_t)s * 2048 + hh * 64 + i;
        float t1 = p[0], t2 = p[32];
        float v1 = t1 * c - t2 * sn, v2 = t2 * c + t1 * sn;
        size_t base = (size_t)s * 1024 + hh * 64 + i;
        f16 h, l;
        fsplit(v1, h, l); QH[base] = h;      QL[base] = l;
        fsplit(v2, h, l); QH[base + 32] = h; QL[base + 32] = l;
    } else {
        const float* p = qkv32 + (size_t)s * 2048 + 1024 + (hh - 16) * 64 + i;
        float t1 = p[0], t2 = p[32];
        float v1 = t1 * c - t2 * sn, v2 = t2 * c + t1 * sn;
        size_t base = (size_t)s * 512 + (hh - 16) * 64 + i;
        f16 h, l;
        fsplit(v1, h, l); KH[base] = h;      KL[base] = l;
        fsplit(v2, h, l); KH[base + 32] = h; KL[base + 32] = l;
    }
}

// ---------------- V transpose + split: qkv32 v-cols -> vt[512][2048] x2 ---------
__global__ void split_v_t(const float* __restrict__ qkv32,
                          f16* __restrict__ vth, f16* __restrict__ vtl) {
    __shared__ float tile[32][33];
    int c0 = blockIdx.x * 32, s0 = blockIdx.y * 32;
    int tx = threadIdx.x & 31, ty = threadIdx.x >> 5;
#pragma unroll
    for (int i = 0; i < 4; ++i)
        tile[ty + 8*i][tx] = qkv32[(size_t)(s0 + ty + 8*i) * 2048 + 1536 + c0 + tx];
    __syncthreads();
#pragma unroll
    for (int i = 0; i < 4; ++i) {
        float v = tile[tx][ty + 8*i];
        f16 h, l; fsplit(v, h, l);
        size_t o = (size_t)(c0 + ty + 8*i) * 2048 + s0 + tx;
        vth[o] = h; vtl[o] = l;
    }
}

// ---------------- flash attention v3: 4-wave blocks, LDS-staged K/V, split-K ----
__launch_bounds__(256, 4)
__global__ void flash_attn_v3(const f16* __restrict__ QH, const f16* __restrict__ QL,
                              const f16* __restrict__ KH, const f16* __restrict__ KL,
                              const f16* __restrict__ VTH, const f16* __restrict__ VTL,
                              float* __restrict__ PO, float* __restrict__ PS) {
    const int c = blockIdx.x;           // K chunk (512 rows)
    const int qt64 = blockIdx.y;        // 64-row q tile
    const int h = blockIdx.z;
    const int qbase64 = qt64 * 64;
    const int kstart = c * 512;
    const int kend_blk = min(kstart + 512, qbase64 + 64);
    if (kstart >= kend_blk) return;     // uniform early exit
    const int kvh = h >> 1;
    const int tid = threadIdx.x;
    const int w = tid >> 6, l = tid & 63;
    const int lo = l & 15, hi = l >> 4;
    const int qbase = qbase64 + w * 16; // this wave's 16 q-rows
    const int kmax_w = qbase + 16;

    __shared__ f16 KHs[2][32 * 64];
    __shared__ f16 KLs[2][32 * 64];
    __shared__ f16 VHs[2][64 * 32];
    __shared__ f16 VLs[2][64 * 32];

    const f16* qrh = QH + (size_t)(qbase + lo) * 1024 + h * 64;
    const f16* qrl = QL + (size_t)(qbase + lo) * 1024 + h * 64;
    f16x8 qh0 = *reinterpret_cast<const f16x8*>(qrh + hi * 8);
    f16x8 qh1 = *reinterpret_cast<const f16x8*>(qrh + 32 + hi * 8);
    f16x8 ql0 = *reinterpret_cast<const f16x8*>(qrl + hi * 8);
    f16x8 ql1 = *reinterpret_cast<const f16x8*>(qrl + 32 + hi * 8);

    f32x4 o0 = (f32x4)0.f, o1 = (f32x4)0.f, o2 = (f32x4)0.f, o3 = (f32x4)0.f;
    f32x4 c0v = (f32x4)0.f, c1v = (f32x4)0.f, c2v = (f32x4)0.f, c3v = (f32x4)0.f;
    float psum = 0.f;
    const int qg = qbase + lo;
    const int srcA = ((2 * hi) & 3) * 16 + lo;
    const int srcB = ((2 * hi + 1) & 3) * 16 + lo;
    const bool th = (hi >= 2);

    // staging lane mapping (per wave: 1KB each of Kh/Kl/Vh/Vl)
    const int rK = w * 8 + (l >> 3), sK = l & 7;
    const int sKg = sK ^ (rK & 7);
    const int dV = w * 16 + (l >> 2), sV = l & 3;
    const int sVg = sV ^ ((dV >> 1) & 3);
    const f16* KHg = KH + (size_t)rK * 512 + kvh * 64 + sKg * 8;
    const f16* KLg = KL + (size_t)rK * 512 + kvh * 64 + sKg * 8;
    const f16* VHg = VTH + (size_t)(kvh * 64 + dV) * 2048 + sVg * 8;
    const f16* VLg = VTL + (size_t)(kvh * 64 + dV) * 2048 + sVg * 8;

    auto stage = [&](int buf, int kb) {
        gload_lds16(KHg + (size_t)kb * 512, (char*)&KHs[buf][0] + w * 1024);
        gload_lds16(KLg + (size_t)kb * 512, (char*)&KLs[buf][0] + w * 1024);
        gload_lds16(VHg + kb,               (char*)&VHs[buf][0] + w * 1024);
        gload_lds16(VLg + kb,               (char*)&VLs[buf][0] + w * 1024);
    };

    const int swk = lo & 7;
    const int swv = (lo >> 1) & 3;
    const int kA = (hi ^ swk) << 4, kB = ((hi + 4) ^ swk) << 4;
    const int vA = (hi ^ swv) << 4;

    auto stepc = [&](int buf, int kb, bool masked) {
        const char* Kh = (const char*)&KHs[buf][0];
        const char* Kl = (const char*)&KLs[buf][0];
        const char* Vh = (const char*)&VHs[buf][0];
        const char* Vl = (const char*)&VLs[buf][0];
        f16x8 kh00 = *reinterpret_cast<const f16x8*>(Kh + lo * 128 + kA);
        f16x8 kh01 = *reinterpret_cast<const f16x8*>(Kh + lo * 128 + kB);
        f16x8 kl00 = *reinterpret_cast<const f16x8*>(Kl + lo * 128 + kA);
        f16x8 kl01 = *reinterpret_cast<const f16x8*>(Kl + lo * 128 + kB);
        f16x8 kh10 = *reinterpret_cast<const f16x8*>(Kh + (16 + lo) * 128 + kA);
        f16x8 kh11 = *reinterpret_cast<const f16x8*>(Kh + (16 + lo) * 128 + kB);
        f16x8 kl10 = *reinterpret_cast<const f16x8*>(Kl + (16 + lo) * 128 + kA);
        f16x8 kl11 = *reinterpret_cast<const f16x8*>(Kl + (16 + lo) * 128 + kB);
        f32x4 z = (f32x4)0.f;
        f32x4 s0h = MFMAH(kh00, qh0, z);  s0h = MFMAH(kh01, qh1, s0h);
        f32x4 s0c = MFMAH(kh00, ql0, z);  s0c = MFMAH(kh01, ql1, s0c);
        s0c = MFMAH(kl00, qh0, s0c);      s0c = MFMAH(kl01, qh1, s0c);
        f32x4 s1h = MFMAH(kh10, qh0, z);  s1h = MFMAH(kh11, qh1, s1h);
        f32x4 s1c = MFMAH(kh10, ql0, z);  s1c = MFMAH(kh11, ql1, s1c);
        s1c = MFMAH(kl10, qh0, s1c);      s1c = MFMAH(kl11, qh1, s1c);

        float p0[4], p1[4];
#pragma unroll
        for (int r = 0; r < 4; ++r) {
            float v0 = (s0h[r] + s0c[r] * INV_LO) * 0.125f;
            float v1 = (s1h[r] + s1c[r] * INV_LO) * 0.125f;
            p0[r] = __expf(v0);
            p1[r] = __expf(v1);
            if (masked) {
                int kg0 = kb + hi * 4 + r;
                if (kg0 > qg)      p0[r] = 0.f;
                if (kg0 + 16 > qg) p1[r] = 0.f;
            }
            psum += p0[r] + p1[r];
        }

        f16 ph[8], pl[8];
#pragma unroll
        for (int r = 0; r < 4; ++r) {
            fsplit(p0[r], ph[r], pl[r]);
            fsplit(p1[r], ph[4 + r], pl[4 + r]);
        }
        u32 hk00 = packh2(ph[0], ph[1]), hk01 = packh2(ph[2], ph[3]);
        u32 hk10 = packh2(ph[4], ph[5]), hk11 = packh2(ph[6], ph[7]);
        u32 lk00 = packh2(pl[0], pl[1]), lk01 = packh2(pl[2], pl[3]);
        u32 lk10 = packh2(pl[4], pl[5]), lk11 = packh2(pl[6], pl[7]);
        union { u32 u[4]; f16x8 v; } pwh, pwl;
        {
            u32 a00 = __shfl(hk00, srcA), a01 = __shfl(hk01, srcA);
            u32 a10 = __shfl(hk10, srcA), a11 = __shfl(hk11, srcA);
            u32 b00 = __shfl(hk00, srcB), b01 = __shfl(hk01, srcB);
            u32 b10 = __shfl(hk10, srcB), b11 = __shfl(hk11, srcB);
            pwh.u[0] = th ? a10 : a00;
            pwh.u[1] = th ? a11 : a01;
            pwh.u[2] = th ? b10 : b00;
            pwh.u[3] = th ? b11 : b01;
        }
        {
            u32 a00 = __shfl(lk00, srcA), a01 = __shfl(lk01, srcA);
            u32 a10 = __shfl(lk10, srcA), a11 = __shfl(lk11, srcA);
            u32 b00 = __shfl(lk00, srcB), b01 = __shfl(lk01, srcB);
            u32 b10 = __shfl(lk10, srcB), b11 = __shfl(lk11, srcB);
            pwl.u[0] = th ? a10 : a00;
            pwl.u[1] = th ? a11 : a01;
            pwl.u[2] = th ? b10 : b00;
            pwl.u[3] = th ? b11 : b01;
        }
        f16x8 pbh = pwh.v, pbl = pwl.v;

        f16x8 vh0 = *reinterpret_cast<const f16x8*>(Vh + (0 * 16 + lo) * 64 + vA);
        f16x8 vh1 = *reinterpret_cast<const f16x8*>(Vh + (1 * 16 + lo) * 64 + vA);
        f16x8 vh2 = *reinterpret_cast<const f16x8*>(Vh + (2 * 16 + lo) * 64 + vA);
        f16x8 vh3 = *reinterpret_cast<const f16x8*>(Vh + (3 * 16 + lo) * 64 + vA);
        f16x8 vl0 = *reinterpret_cast<const f16x8*>(Vl + (0 * 16 + lo) * 64 + vA);
        f16x8 vl1 = *reinterpret_cast<const f16x8*>(Vl + (1 * 16 + lo) * 64 + vA);
        f16x8 vl2 = *reinterpret_cast<const f16x8*>(Vl + (2 * 16 + lo) * 64 + vA);
        f16x8 vl3 = *reinterpret_cast<const f16x8*>(Vl + (3 * 16 + lo) * 64 + vA);
        o0 = MFMAH(vh0, pbh, o0);
        o1 = MFMAH(vh1, pbh, o1);
        o2 = MFMAH(vh2, pbh, o2);
        o3 = MFMAH(vh3, pbh, o3);
        c0v = MFMAH(vh0, pbl, c0v);  c0v = MFMAH(vl0, pbh, c0v);
        c1v = MFMAH(vh1, pbl, c1v);  c1v = MFMAH(vl1, pbh, c1v);
        c2v = MFMAH(vh2, pbl, c2v);  c2v = MFMAH(vl2, pbh, c2v);
        c3v = MFMAH(vh3, pbl, c3v);  c3v = MFMAH(vl3, pbh, c3v);
    };

    int buf = 0;
    stage(0, kstart);
    for (int kb = kstart; kb < kend_blk; kb += 32) {
        __syncthreads();                       // staged buf ready (vmcnt drained)
        if (kb + 32 < kend_blk) stage(buf ^ 1, kb + 32);
        if (kb < kmax_w)
            stepc(buf, kb, kb + 32 > qbase);
        buf ^= 1;
    }

    if (kstart < kmax_w) {
        float ls = psum;
        ls += __shfl_xor(ls, 16);
        ls += __shfl_xor(ls, 32);
        const int qt16 = qt64 * 4 + w;
        const size_t slot = ((size_t)(h * 128 + qt16) * 4 + c);
        float* po = PO + slot * 1024;
#pragma unroll
        for (int r = 0; r < 4; ++r) {
            po[lo * 64 + 0  + hi * 4 + r] = o0[r] + c0v[r] * INV_LO;
            po[lo * 64 + 16 + hi * 4 + r] = o1[r] + c1v[r] * INV_LO;
            po[lo * 64 + 32 + hi * 4 + r] = o2[r] + c2v[r] * INV_LO;
            po[lo * 64 + 48 + hi * 4 + r] = o3[r] + c3v[r] * INV_LO;
        }
        if (l < 16) PS[slot * 16 + lo] = ls;
    }
}

// ---------------- combine split-K partials -> split-f16 ATTN --------------------
__global__ void attn_combine(const float* __restrict__ PO, const float* __restrict__ PS,
                             f16* __restrict__ AH, f16* __restrict__ AL) {
    const int s = blockIdx.x, t = threadIdx.x;   // s: token row, t*4: dim
    const int qt = s >> 4, r = s & 15;
    const int nc = (qt * 16 + 16 + 511) >> 9;
    const int d0 = t * 4;
    const int h = d0 >> 6;
    const size_t sbase = (size_t)(h * 128 + qt) * 4;
    float4 acc = make_float4(0.f, 0.f, 0.f, 0.f);
    float ps = 0.f;
    for (int c = 0; c < nc; ++c) {
        const float4 v = *reinterpret_cast<const float4*>(
            PO + (sbase + c) * 1024 + r * 64 + (d0 & 63));
        acc.x += v.x; acc.y += v.y; acc.z += v.z; acc.w += v.w;
        ps += PS[(sbase + c) * 16 + r];
    }
    float inv = 1.f / ps;
    union { f16 f[4]; ushort4 u; } H, L;
    fsplit(acc.x * inv, H.f[0], L.f[0]);
    fsplit(acc.y * inv, H.f[1], L.f[1]);
    fsplit(acc.z * inv, H.f[2], L.f[2]);
    fsplit(acc.w * inv, H.f[3], L.f[3]);
    reinterpret_cast<ushort4*>((u16*)AH + (size_t)s * 1024)[t] = H.u;
    reinterpret_cast<ushort4*>((u16*)AL + (size_t)s * 1024)[t] = L.u;
}

// ---------------- MoE up-projection: BM=256, BN=128 (w1/w3 interleaved) ---------
// bx in [0,44): each block covers W13T rows [bx*128, bx*128+128) = 64 output
// features (w1 rows at +0..63, w3 rows at +64..127). Silu fuse intra-thread.
__launch_bounds__(256, 2)
__global__ void moe_up(const u16* __restrict__ A, const u16* __restrict__ B13,
                       u16* __restrict__ ACT,
                       const int* __restrict__ e_cnt, const int* __restrict__ e_off,
                       const int* __restrict__ glist) {
    const int e = blockIdx.z;
    const int Me = e_cnt[e], off = e_off[e];
    const int by = blockIdx.y, bx = blockIdx.x;   // bx in [0,44)
    if (by * 256 >= Me) return;
    const u16* Be = B13 + (size_t)e * 5632 * 1024;

    __shared__ u16 As[256 * 64];
    __shared__ u16 Bs[128 * 64];

    const int tid = threadIdx.x;
    const int l = tid & 63, w = tid >> 6;
    const int lo = l & 15, hi = l >> 4;

    f32x4 acc[4][8];
#pragma unroll
    for (int i = 0; i < 4; ++i)
#pragma unroll
        for (int j = 0; j < 8; ++j) acc[i][j] = (f32x4)0.f;

    const int srow = tid >> 3;          // 0..31 within each 32-row group
    const int colb = (tid & 7) * 16;    // byte col within 128B row
    int arow[8];
#pragma unroll
    for (int i = 0; i < 8; ++i) {
        int ml = by * 256 + i * 32 + srow;
        if (ml > Me - 1) ml = Me - 1;
        arow[i] = glist[off + ml];
    }
    const int brow = bx * 128 + srow;

    for (int k0 = 0; k0 < 1024; k0 += 64) {
#pragma unroll
        for (int i = 0; i < 8; ++i)
            gload_lds16(A + (size_t)arow[i] * 1024 + k0 + (colb >> 1),
                        (char*)As + i * 4096 + w * 1024);
#pragma unroll
        for (int i = 0; i < 4; ++i)
            gload_lds16(Be + (size_t)(brow + i * 32) * 1024 + k0 + (colb >> 1),
                        (char*)Bs + i * 4096 + w * 1024);
        __syncthreads();
#pragma unroll
        for (int kk = 0; kk < 2; ++kk) {
            bf16x8 af[4], bf[8];
#pragma unroll
            for (int mi = 0; mi < 4; ++mi)
                af[mi] = *reinterpret_cast<const bf16x8*>(
                    (const char*)As + (w * 64 + mi * 16 + lo) * 128 + kk * 64 + hi * 16);
#pragma unroll
            for (int ni = 0; ni < 8; ++ni)
                bf[ni] = *reinterpret_cast<const bf16x8*>(
                    (const char*)Bs + (ni * 16 + lo) * 128 + kk * 64 + hi * 16);
#pragma unroll
            for (int mi = 0; mi < 4; ++mi)
#pragma unroll
                for (int ni = 0; ni < 8; ++ni)
                    acc[mi][ni] = MFMAB(af[mi], bf[ni], acc[mi][ni]);
        }
        __syncthreads();
    }
#pragma unroll
    for (int mi = 0; mi < 4; ++mi)
#pragma unroll
        for (int ni = 0; ni < 4; ++ni)
#pragma unroll
            for (int r = 0; r < 4; ++r) {
                int ml = by * 256 + w * 64 + mi * 16 + hi * 4 + r;
                if (ml < Me) {
                    int nc = bx * 64 + ni * 16 + lo;
                    float hh = acc[mi][ni][r], gg = acc[mi][ni + 4][r];
                    float sg = hh / (1.f + __expf(-hh));
                    ACT[(size_t)(off + ml) * 2816 + nc] = f2bf(sg * gg);
                }
            }
}

// ---------------- MoE down-projection: BM=256, BN=128, SPLIT-K x4 ---------------
// 4 waves as 2M x 2N, wave-tile 128x64 (MR=8, NR=4). LDS 48 KB.
// blockIdx.x = bx (0..7) | ks<<3 (0..3); K chunk = [ks*704, ks*704+704).
__launch_bounds__(256, 2)
__global__ void moe_down(const u16* __restrict__ ACT, const u16* __restrict__ B2,
                         float* __restrict__ YP,
                         const int* __restrict__ e_cnt, const int* __restrict__ e_off) {
    const int e = blockIdx.z;
    const int Me = e_cnt[e], off = e_off[e];
    const int by = blockIdx.y;
    const int bx = blockIdx.x & 7;
    const int ks = blockIdx.x >> 3;
    if (by * 256 >= Me) return;
    const u16* Be = B2 + (size_t)e * 1024 * 2816;

    __shared__ u16 As[256 * 64];
    __shared__ u16 Bs[128 * 64];

    const int tid = threadIdx.x;
    const int l = tid & 63, w = tid >> 6;
    const int lo = l & 15, hi = l >> 4;
    const int wm = w >> 1, wn = w & 1;

    f32x4 acc[8][4];
#pragma unroll
    for (int i = 0; i < 8; ++i)
#pragma unroll
        for (int j = 0; j < 4; ++j) acc[i][j] = (f32x4)0.f;

    const int srow = tid >> 3;
    const int colb = (tid & 7) * 16;
    int amrow[8];
#pragma unroll
    for (int i = 0; i < 8; ++i) {
        int ml = by * 256 + i * 32 + srow;
        if (ml > Me - 1) ml = Me - 1;
        amrow[i] = off + ml;
    }
    const int brow = bx * 128 + srow;

    const int kbeg = ks * 704, kend = kbeg + 704;
    for (int k0 = kbeg; k0 < kend; k0 += 64) {
#pragma unroll
        for (int i = 0; i < 8; ++i)
            gload_lds16(ACT + (size_t)amrow[i] * 2816 + k0 + (colb >> 1),
                        (char*)As + i * 4096 + w * 1024);
#pragma unroll
        for (int i = 0; i < 4; ++i)
            gload_lds16(Be + (size_t)(brow + i * 32) * 2816 + k0 + (colb >> 1),
                        (char*)Bs + i * 4096 + w * 1024);
        __syncthreads();
#pragma unroll
        for (int kk = 0; kk < 2; ++kk) {
            bf16x8 af[8], bf[4];
#pragma unroll
            for (int mi = 0; mi < 8; ++mi)
                af[mi] = *reinterpret_cast<const bf16x8*>(
                    (const char*)As + (wm * 128 + mi * 16 + lo) * 128 + kk * 64 + hi * 16);
#pragma unroll
            for (int ni = 0; ni < 4; ++ni)
                bf[ni] = *reinterpret_cast<const bf16x8*>(
                    (const char*)Bs + (wn * 64 + ni * 16 + lo) * 128 + kk * 64 + hi * 16);
#pragma unroll
            for (int mi = 0; mi < 8; ++mi)
#pragma unroll
                for (int ni = 0; ni < 4; ++ni)
                    acc[mi][ni] = MFMAB(af[mi], bf[ni], acc[mi][ni]);
        }
        __syncthreads();
    }
    float* Yk = YP + (size_t)ks * YSTR;
#pragma unroll
    for (int mi = 0; mi < 8; ++mi)
#pragma unroll
        for (int ni = 0; ni < 4; ++ni)
#pragma unroll
            for (int r = 0; r < 4; ++r) {
                int ml = by * 256 + wm * 128 + mi * 16 + hi * 4 + r;
                if (ml < Me) {
                    int nc = bx * 128 + wn * 64 + ni * 16 + lo;
                    Yk[(size_t)(off + ml) * 1024 + nc] = acc[mi][ni][r];
                }
            }
}

// ---------------- router (full f32, 1 wave / token) -----------------------------
__global__ void router_kernel(const float* __restrict__ x2, const float* __restrict__ ln2w,
                              const float* __restrict__ wr,
                              int* __restrict__ topi, float* __restrict__ topw) {
    const int t = blockIdx.x, l = threadIdx.x;
    float ss = 0.f;
    float acc[8] = {0.f,0.f,0.f,0.f,0.f,0.f,0.f,0.f};
    const float* xr = x2 + (size_t)t * 1024;
    for (int d = l; d < 1024; d += 64) {
        float xv = xr[d];
        ss += xv * xv;
        float xw = xv * ln2w[d];
        const float* wrow = wr + (size_t)d * 8;
#pragma unroll
        for (int e2 = 0; e2 < 8; ++e2) acc[e2] += xw * wrow[e2];
    }
#pragma unroll
    for (int o = 32; o >= 1; o >>= 1) {
        ss += __shfl_xor(ss, o);
#pragma unroll
        for (int e2 = 0; e2 < 8; ++e2) acc[e2] += __shfl_xor(acc[e2], o);
    }
    if (l == 0) {
        float inv = rsqrtf(ss * (1.f/1024.f) + 1e-6f);
        float pe[8]; float mx = -3e38f;
#pragma unroll
        for (int e2 = 0; e2 < 8; ++e2) { pe[e2] = acc[e2] * inv; mx = fmaxf(mx, pe[e2]); }
#pragma unroll
        for (int e2 = 0; e2 < 8; ++e2) pe[e2] = expf(pe[e2] - mx);
        int i0 = 0; float b0 = -1.f;
#pragma unroll
        for (int e2 = 0; e2 < 8; ++e2) if (pe[e2] > b0) { b0 = pe[e2]; i0 = e2; }
        int i1 = -1; float b1 = -1.f;
#pragma unroll
        for (int e2 = 0; e2 < 8; ++e2) if (e2 != i0 && pe[e2] > b1) { b1 = pe[e2]; i1 = e2; }
        float wsum = b0 + b1;
        topi[2*t] = i0;  topi[2*t+1] = i1;
        topw[2*t] = b0 / wsum;  topw[2*t+1] = b1 / wsum;
    }
}

__global__ void moe_count(const int* __restrict__ topi, int* __restrict__ cnt) {
    __shared__ int lh[8];
    int t = threadIdx.x;
    if (t < 8) lh[t] = 0;
    __syncthreads();
    int tok = blockIdx.x * 256 + t;
    if (tok < 2048) {
        atomicAdd(&lh[topi[2*tok]], 1);
        atomicAdd(&lh[topi[2*tok+1]], 1);
    }
    __syncthreads();
    if (t < 8) atomicAdd(&cnt[t], lh[t]);
}

__global__ void moe_offsets(const int* __restrict__ cnt, int* __restrict__ offp) {
    if (threadIdx.x == 0 && blockIdx.x == 0) {
        int s = 0;
        for (int e2 = 0; e2 < 8; ++e2) { offp[e2] = s; s += cnt[e2]; }
    }
}

__global__ void moe_assign(const int* __restrict__ topi, const int* __restrict__ offp,
                           int* __restrict__ cur, int* __restrict__ tok_of,
                           int* __restrict__ slot_of) {
    int tok = blockIdx.x * 256 + threadIdx.x;
    if (tok < 2048) {
#pragma unroll
        for (int j = 0; j < 2; ++j) {
            int e2 = topi[2*tok + j];
            int s = atomicAdd(&cur[e2], 1);
            int g = offp[e2] + s;
            tok_of[g] = tok;
            slot_of[2*tok + j] = g;
        }
    }
}

// sums 4 split-K partials per slot (fixed order -> deterministic)
__global__ void combine_kernel(const float* __restrict__ x2, const float* __restrict__ yp,
                               const int* __restrict__ slot_of, const float* __restrict__ topw,
                               float* __restrict__ outp) {
    int t = blockIdx.x, i = threadIdx.x;
    int s0 = slot_of[2*t], s1 = slot_of[2*t+1];
    float w0 = topw[2*t], w1 = topw[2*t+1];
    float4 a = reinterpret_cast<const float4*>(x2 + (size_t)t * 1024)[i];
    float4 y0 = make_float4(0.f, 0.f, 0.f, 0.f);
    float4 y1 = make_float4(0.f, 0.f, 0.f, 0.f);
#pragma unroll
    for (int ks = 0; ks < 4; ++ks) {
        const float4 v0 = reinterpret_cast<const float4*>(yp + ks * YSTR + (size_t)s0 * 1024)[i];
        const float4 v1 = reinterpret_cast<const float4*>(yp + ks * YSTR + (size_t)s1 * 1024)[i];
        y0.x += v0.x; y0.y += v0.y; y0.z += v0.z; y0.w += v0.w;
        y1.x += v1.x; y1.y += v1.y; y1.z += v1.z; y1.w += v1.w;
    }
    float4 r;
    r.x = a.x + w0 * y0.x + w1 * y1.x;
    r.y = a.y + w0 * y0.y + w1 * y1.y;
    r.z = a.z + w0 * y0.z + w1 * y1.z;
    r.w = a.w + w0 * y0.w + w1 * y1.w;
    reinterpret_cast<float4*>(outp + (size_t)t * 1024)[i] = r;
}

// ================================================================================
extern "C" void kernel_launch(void* const* d_in, const int* in_sizes, int n_in,
                              void* d_out, int out_size, void* d_ws, size_t ws_size,
                              hipStream_t stream) {
    (void)in_sizes; (void)n_in; (void)out_size; (void)ws_size;
    const float* x    = (const float*)d_in[0];
    const float* ln1w = (const float*)d_in[3];
    const float* wq   = (const float*)d_in[4];
    const float* wk   = (const float*)d_in[5];
    const float* wv   = (const float*)d_in[6];
    const float* wo   = (const float*)d_in[7];
    const float* ln2w = (const float*)d_in[8];
    const float* wr   = (const float*)d_in[9];
    const float* w1   = (const float*)d_in[10];
    const float* w3   = (const float*)d_in[11];
    const float* w2   = (const float*)d_in[12];
    float* outp = (float*)d_out;

    char* ws = (char*)d_ws;
    size_t off = 0;
    auto alloc = [&](size_t bytes) -> char* {
        char* p = ws + off;
        off += (bytes + 255) & ~(size_t)255;
        return p;
    };
    // persistent weights (split f16 attention, bf16 MoE)
    f16* WQKVTH = (f16*)alloc(2048ull * 1024 * 2);
    f16* WQKVTL = (f16*)alloc(2048ull * 1024 * 2);
    f16* WOTH   = (f16*)alloc(1024ull * 1024 * 2);
    f16* WOTL   = (f16*)alloc(1024ull * 1024 * 2);
    u16* W13T   = (u16*)alloc(8ull * 5632 * 1024 * 2);   // w1/w3 interleaved
    u16* W2T    = (u16*)alloc(8ull * 1024 * 2816 * 2);
    // persistent activations
    float* X2   = (float*)alloc(2048ull * 1024 * 4);
    u16*  XN2   = (u16*)alloc(2048ull * 1024 * 2);
    float* CT   = (float*)alloc(2048ull * 32 * 4);
    float* ST   = (float*)alloc(2048ull * 32 * 4);
    int*  TOPI  = (int*)alloc(2048 * 2 * 4);
    float* TOPW = (float*)alloc(2048 * 2 * 4);
    int*  SLOT  = (int*)alloc(2048 * 2 * 4);
    int*  TOK   = (int*)alloc(4224 * 4);
    int*  CNT   = (int*)alloc(8 * 4);
    int*  CUR   = (int*)alloc(8 * 4);
    int*  OFFP  = (int*)alloc(8 * 4);
    // aliased arena: attention temps, then MoE temps
    size_t arena_start = off;
    f16* XN1H = (f16*)alloc(2048ull * 1024 * 2);
    f16* XN1L = (f16*)alloc(2048ull * 1024 * 2);
    float* QKV32 = (float*)alloc(2048ull * 2048 * 4);
    f16* QH = (f16*)alloc(2048ull * 1024 * 2);
    f16* QL = (f16*)alloc(2048ull * 1024 * 2);
    f16* KH = (f16*)alloc(2048ull * 512 * 2);
    f16* KL = (f16*)alloc(2048ull * 512 * 2);
    f16* VTH = (f16*)alloc(512ull * 2048 * 2);
    f16* VTL = (f16*)alloc(512ull * 2048 * 2);
    f16* ATTNH = (f16*)alloc(2048ull * 1024 * 2);
    f16* ATTNL = (f16*)alloc(2048ull * 1024 * 2);
    float* PO  = (float*)alloc(8192ull * 1024 * 4);   // split-K partial O
    float* PS  = (float*)alloc(8192ull * 16 * 4);     // split-K partial psum
    size_t arena_end_attn = off;
    // MoE arena aliases the attention arena
    off = arena_start;
    u16*  ACT = (u16*)alloc((4096ull + 256) * 2816 * 2);
    float* YP = (float*)alloc(4ull * YSTR * 4);       // 4 split-K partial Y buffers
    if (off < arena_end_attn) off = arena_end_attn;

    hipMemsetAsync(CNT, 0, 32, stream);
    hipMemsetAsync(CUR, 0, 32, stream);

    dim3 tb(256);
    // weight prep
    transpose_wsplit<<<dim3(32, 32), tb, 0, stream>>>(wq, WQKVTH, WQKVTL, 1024, 1024);
    transpose_wsplit<<<dim3(16, 32), tb, 0, stream>>>(wk, WQKVTH + 1024ull*1024, WQKVTL + 1024ull*1024, 1024, 512);
    transpose_wsplit<<<dim3(16, 32), tb, 0, stream>>>(wv, WQKVTH + 1536ull*1024, WQKVTL + 1536ull*1024, 1024, 512);
    transpose_wsplit<<<dim3(32, 32), tb, 0, stream>>>(wo, WOTH, WOTL, 1024, 1024);
    transpose_w13<<<dim3(88, 32, 8), tb, 0, stream>>>(w1, W13T, 0);
    transpose_w13<<<dim3(88, 32, 8), tb, 0, stream>>>(w3, W13T, 64);
    transpose_wb<<<dim3(32, 88, 8), tb, 0, stream>>>(w2, W2T, 2816, 1024);

    rope_tables<<<dim3((2048 * 32 + 255) / 256), tb, 0, stream>>>(CT, ST);
    rmsnorm_split<<<dim3(2048), tb, 0, stream>>>(x, ln1w, XN1H, XN1L);

    // QKV projection (split precision, f32 out)
    gemm_split<0><<<dim3(16, 16), tb, 0, stream>>>(
        XN1H, XN1L, WQKVTH, WQKVTL, QKV32, nullptr, 1024, 2048);

    rope_split<<<dim3((2048 * 768 + 255) / 256), tb, 0, stream>>>(QKV32, CT, ST, QH, QL, KH, KL);
    split_v_t<<<dim3(16, 64), tb, 0, stream>>>(QKV32, VTH, VTL);

    // LDS-staged split-K flash attention + combine
    flash_attn_v3<<<dim3(4, 32, 16), tb, 0, stream>>>(
        QH, QL, KH, KL, VTH, VTL, PO, PS);
    attn_combine<<<dim3(2048), tb, 0, stream>>>(PO, PS, ATTNH, ATTNL);

    // output projection + residual -> X2 (f32)
    gemm_split<1><<<dim3(8, 16), tb, 0, stream>>>(
        ATTNH, ATTNL, WOTH, WOTL, X2, x, 1024, 1024);

    router_kernel<<<dim3(2048), dim3(64), 0, stream>>>(X2, ln2w, wr, TOPI, TOPW);
    rmsnorm_bf16<<<dim3(2048), tb, 0, stream>>>(X2, ln2w, XN2);
    moe_count<<<dim3(8), tb, 0, stream>>>(TOPI, CNT);
    moe_offsets<<<dim3(1), dim3(64), 0, stream>>>(CNT, OFFP);
    moe_assign<<<dim3(8), tb, 0, stream>>>(TOPI, OFFP, CUR, TOK, SLOT);

    // MoE up-projection, BM=256 x BN=128 (interleaved w1/w3), bx in [0,44)
    moe_up<<<dim3(44, 8, 8), tb, 0, stream>>>(
        XN2, W13T, ACT, CNT, OFFP, TOK);

    // MoE down-projection, BM=256 x BN=128, split-K x4
    moe_down<<<dim3(32, 8, 8), tb, 0, stream>>>(
        ACT, W2T, YP, CNT, OFFP);

    combine_kernel<<<dim3(2048), tb, 0, stream>>>(X2, YP, SLOT, TOPW, outp);
}